// Round 9
// baseline (306.345 us; speedup 1.0000x reference)
//
#include <hip/hip_runtime.h>
#include <hip/hip_bf16.h>
#include <math.h>

#define Bn 64
#define Tn 256
#define Cn 384
#define Hn 6
#define HSn 64
#define FFn 1536
#define EPSn 1e-3f
#define SECn 6291456  // B*H*T*HS = one q/k/v section, elements

typedef __attribute__((ext_vector_type(4))) float f32x4;
typedef __attribute__((ext_vector_type(2))) float f32x2;
typedef __attribute__((ext_vector_type(8))) short short8;
typedef __attribute__((ext_vector_type(4))) short short4v;
typedef __attribute__((ext_vector_type(2))) short short2v;

__device__ __forceinline__ void async_copy16(void* lds, const void* g) {
    __builtin_amdgcn_global_load_lds(
        (const __attribute__((address_space(1))) void*)g,
        (__attribute__((address_space(3))) void*)lds, 16, 0, 0);
}

__device__ __forceinline__ short f2bf(float v) {
    __hip_bfloat16 h = __float2bfloat16(v);
    return *(short*)&h;
}

// ---------------- LayerNorm -> bf16 (one wave per row, vectorized) ----------------
__global__ __launch_bounds__(64) void ln_bf16_kernel(const float* __restrict__ x,
                                                     const float* __restrict__ g,
                                                     const float* __restrict__ be,
                                                     __hip_bfloat16* __restrict__ out) {
    int row = blockIdx.x;
    int lane = threadIdx.x;
    const float* xr = x + (size_t)row * Cn;
    f32x4 a = *(const f32x4*)(xr + lane * 4);
    f32x2 b = *(const f32x2*)(xr + 256 + lane * 2);
    float s = a.x + a.y + a.z + a.w + b.x + b.y;
#pragma unroll
    for (int off = 32; off; off >>= 1) s += __shfl_xor(s, off);
    float mu = s * (1.0f / Cn);
    f32x4 da = a - mu;
    f32x2 db = b - mu;
    float sq = da.x * da.x + da.y * da.y + da.z * da.z + da.w * da.w + db.x * db.x + db.y * db.y;
#pragma unroll
    for (int off = 32; off; off >>= 1) sq += __shfl_xor(sq, off);
    float r = rsqrtf(sq * (1.0f / Cn) + EPSn);
    f32x4 g4 = *(const f32x4*)(g + lane * 4);
    f32x2 g2 = *(const f32x2*)(g + 256 + lane * 2);
    f32x4 e4 = *(const f32x4*)(be + lane * 4);
    f32x2 e2 = *(const f32x2*)(be + 256 + lane * 2);
    f32x4 y4 = da * r * g4 + e4;
    f32x2 y2 = db * r * g2 + e2;
    short* orow = (short*)out + (size_t)row * Cn;
    short4v o4 = {f2bf(y4.x), f2bf(y4.y), f2bf(y4.z), f2bf(y4.w)};
    *(short4v*)(orow + lane * 4) = o4;
    short2v o2 = {f2bf(y2.x), f2bf(y2.y)};
    *(short2v*)(orow + 256 + lane * 2) = o2;
}

// ---------------- Pack a [K,N] row-major fp32 weight into MFMA B-fragment order ----------------
__global__ __launch_bounds__(256) void pack_b_kernel(const float* __restrict__ W,
                                                     __hip_bfloat16* __restrict__ out,
                                                     int K, int N) {
    int id = blockIdx.x * 256 + threadIdx.x;
    if (id >= K * N) return;
    int tile = id >> 9, lane = (id >> 3) & 63, j = id & 7;
    int ntiles = N >> 4;
    int k = (tile / ntiles) * 32 + ((lane >> 4) << 3) + j;
    int n = (tile % ntiles) * 16 + (lane & 15);
    out[id] = __float2bfloat16(W[(size_t)k * N + n]);
}

// ---------------- Pack fused [Wq|Wk|Wv] into one B [K=384, N=1152] ----------------
__global__ __launch_bounds__(256) void pack_qkv_kernel(const float* __restrict__ Wq,
                                                       const float* __restrict__ Wk,
                                                       const float* __restrict__ Wv,
                                                       __hip_bfloat16* __restrict__ out) {
    int id = blockIdx.x * 256 + threadIdx.x;
    if (id >= Cn * 1152) return;
    int tile = id >> 9, lane = (id >> 3) & 63, j = id & 7;
    int k = (tile / 72) * 32 + ((lane >> 4) << 3) + j;
    int n = (tile % 72) * 16 + (lane & 15);
    int sec = n / Cn, rem = n % Cn;
    int hh = rem >> 6, d = rem & 63;
    const float* W = (sec == 0) ? Wq : ((sec == 1) ? Wk : Wv);
    out[id] = __float2bfloat16(W[((size_t)hh * Cn + k) * HSn + d]);
}

// ---------------- MFMA GEMM, LDS-staged, vectorized LDS-transpose epilogue ----------------
// Block tile 128(M) x 64(N), BK=32. XCD swizzle keeps a rowblk's colblks on one XCD.
// Epilogue: acc (C-layout) -> per-wave LDS strip [row][col] -> 16B/lane coalesced stores.
template <int KK, int NN, int EPI>
__global__ __launch_bounds__(256) void gemm_mfma(const __hip_bfloat16* __restrict__ A,
                                                 const __hip_bfloat16* __restrict__ Bp,
                                                 const float* __restrict__ bias,
                                                 const float* __restrict__ resid,
                                                 float* __restrict__ outF,
                                                 __hip_bfloat16* __restrict__ outB) {
    constexpr int GX = NN / 64;
    __shared__ __align__(16) char lds_raw[4 * 4864];  // staging (12 KB) U transpose (19 KB)
    short* Atile = (short*)lds_raw;        // 8 KB
    short* Btile = (short*)lds_raw + 4096; // 4 KB

    int l = blockIdx.x;
    int xcd = l & 7, i = l >> 3;
    int rowblk = xcd * 16 + i / GX;
    int colblk = i - (i / GX) * GX;

    int lane = threadIdx.x & 63, wave = threadIdx.x >> 6;
    int lrow = lane & 15, lquad = lane >> 4;
    int m0 = rowblk * 128;
    int n0 = colblk * 64;

    f32x4 acc[2][4];
#pragma unroll
    for (int st = 0; st < 2; st++)
#pragma unroll
        for (int nt = 0; nt < 4; nt++) acc[st][nt] = (f32x4){0.f, 0.f, 0.f, 0.f};

    const short* As = (const short*)A;
    const short* Bs = (const short*)Bp;

    for (int kb = 0; kb < KK; kb += 32) {
        __syncthreads();
#pragma unroll
        for (int p = 0; p < 2; p++) {
            int s = p * 4 + wave;
            const short* ga = As + (size_t)(m0 + s * 16 + lrow) * KK + kb + lquad * 8;
            async_copy16(&Atile[s * 512], ga);
        }
        {
            int tb0 = (kb >> 5) * (NN >> 4) + (n0 >> 4);
            const short* gb = Bs + (size_t)(tb0 + wave) * 512 + lane * 8;
            async_copy16(&Btile[wave * 512], gb);
        }
        __syncthreads();
        short8 af0 = *(const short8*)(&Atile[(2 * wave) * 512 + lane * 8]);
        short8 af1 = *(const short8*)(&Atile[(2 * wave + 1) * 512 + lane * 8]);
#pragma unroll
        for (int nt = 0; nt < 4; nt++) {
            short8 bf = *(const short8*)(&Btile[nt * 512 + lane * 8]);
            acc[0][nt] = __builtin_amdgcn_mfma_f32_16x16x32_bf16(af0, bf, acc[0][nt], 0, 0, 0);
            acc[1][nt] = __builtin_amdgcn_mfma_f32_16x16x32_bf16(af1, bf, acc[1][nt], 0, 0, 0);
        }
    }

    __syncthreads();  // staging LDS is being repurposed as transpose buffers

    if (EPI == 1) {
        // fp32 out = resid + acc + bias, strip-by-strip (16 rows x 64 cols fp32, stride 76)
        float* twf = (float*)(lds_raw + wave * 4864);
        float bnv[4];
#pragma unroll
        for (int nt = 0; nt < 4; nt++) bnv[nt] = bias[n0 + nt * 16 + lrow];
#pragma unroll
        for (int st = 0; st < 2; st++) {
            int mbase = m0 + (2 * wave + st) * 16;
#pragma unroll
            for (int nt = 0; nt < 4; nt++)
#pragma unroll
                for (int r = 0; r < 4; r++)
                    twf[(lquad * 4 + r) * 76 + nt * 16 + lrow] = acc[st][nt][r] + bnv[nt];
            int row = lane >> 2, seg = lane & 3;
            int m = mbase + row;
            const float* rrow = resid + (size_t)m * NN + n0 + seg * 16;
            float* orow = outF + (size_t)m * NN + n0 + seg * 16;
#pragma unroll
            for (int c = 0; c < 4; c++) {
                f32x4 vv = *(const f32x4*)(&twf[row * 76 + seg * 16 + c * 4]);
                f32x4 rv = *(const f32x4*)(rrow + c * 4);
                *(f32x4*)(orow + c * 4) = vv + rv;
            }
            __builtin_amdgcn_s_waitcnt(0);  // lgkm+vm drain before strip reuse (cheap, correct)
        }
    } else {
        // bf16 cases: full 32 rows x 64 cols strip (stride 72 shorts)
        short* tws = (short*)(lds_raw + wave * 4864);
        float bnv[4];
        if (EPI == 2) {
#pragma unroll
            for (int nt = 0; nt < 4; nt++) bnv[nt] = bias[n0 + nt * 16 + lrow];
        }
#pragma unroll
        for (int st = 0; st < 2; st++)
#pragma unroll
            for (int nt = 0; nt < 4; nt++)
#pragma unroll
                for (int r = 0; r < 4; r++) {
                    float v = acc[st][nt][r];
                    if (EPI == 2) v = fmaxf(v + bnv[nt], 0.0f);
                    tws[(st * 16 + lquad * 4 + r) * 72 + nt * 16 + lrow] = f2bf(v);
                }
        if (EPI == 2) {
            int row = lane >> 1, seg = lane & 1;
            int m = m0 + wave * 32 + row;
            short* orow = (short*)outB + (size_t)m * NN + n0 + seg * 32;
#pragma unroll
            for (int c = 0; c < 4; c++) {
                short8 v8 = *(const short8*)(&tws[row * 72 + seg * 32 + c * 8]);
                *(short8*)(orow + c * 8) = v8;
            }
        } else {
            int sec = n0 / 384;
            int rem0 = n0 - sec * 384;
            int hh = rem0 >> 6;  // wave-uniform (64 | 384)
            if (sec < 2) {
                int row = lane >> 1, seg = lane & 1;
                int m = m0 + wave * 32 + row;
                int b = m >> 8, t = m & 255;
                short* orow = (short*)outB + (size_t)sec * SECn +
                              ((((size_t)b * Hn + hh) << 8) + t) * HSn + seg * 32;
#pragma unroll
                for (int c = 0; c < 4; c++) {
                    short8 v8 = *(const short8*)(&tws[row * 72 + seg * 32 + c * 8]);
                    *(short8*)(orow + c * 8) = v8;
                }
            } else {
                // V: store pre-packed B-fragment tiles
                int b = m0 >> 8;
                int t_base = (m0 & 255) + wave * 32;
                int bh2 = b * Hn + hh;
                short* vout = (short*)outB + (size_t)2 * SECn + (size_t)bh2 * 16384 +
                              (size_t)((t_base >> 5) * 4) * 512;
#pragma unroll
                for (int dt = 0; dt < 4; dt++) {
                    short8 v8;
#pragma unroll
                    for (int j = 0; j < 8; j++) {
                        int t_loc = ((lane >> 4) << 3) + j;
                        v8[j] = tws[t_loc * 72 + dt * 16 + (lane & 15)];
                    }
                    *(short8*)(vout + dt * 512 + lane * 8) = v8;
                }
            }
        }
    }
}

// ---------------- Flash-style MFMA attention: one block per (b,h), K in LDS ----------------
__global__ __launch_bounds__(256) void attn_mfma_kernel(const __hip_bfloat16* __restrict__ q,
                                                        const __hip_bfloat16* __restrict__ k,
                                                        const __hip_bfloat16* __restrict__ vp,
                                                        __hip_bfloat16* __restrict__ o) {
    __shared__ short Kl[16 * 1024];  // 32 KB: K tiles [st][chunk<2][512]
    __shared__ short Pl[4 * 4096];   // 32 KB: per-wave P in A-frag layout
    int bh = blockIdx.x;
    int b = bh / Hn, hh = bh - b * Hn;
    int tid = threadIdx.x;
    int lane = tid & 63, wave = tid >> 6;
    int c16 = lane & 15, quad = lane >> 4;

    const short* qs = (const short*)q + (size_t)bh * Tn * HSn;
    const short* ks = (const short*)k + (size_t)bh * Tn * HSn;
    const short* vs = (const short*)vp + (size_t)bh * 16384;  // packed B-frag tiles

#pragma unroll
    for (int i = 0; i < 4; i++) {
        int st = wave * 4 + i;
        const short* g0 = ks + (st * 16 + c16) * HSn + quad * 8;
        async_copy16(&Kl[st * 1024], g0);
        async_copy16(&Kl[st * 1024 + 512], g0 + 32);
    }
    __syncthreads();

    short* Pw = Pl + wave * 4096;

#pragma unroll
    for (int j = 0; j < 4; j++) {
        int qt = j * 4 + wave;
        int qrow0 = qt * 16;
        int st_max = qt;
        int kb_count = (st_max + 2) >> 1;
        int covered = kb_count * 2;

        const short* qrow = qs + (qrow0 + c16) * HSn + quad * 8;
        short8 aq0 = *(const short8*)(qrow);
        short8 aq1 = *(const short8*)(qrow + 32);

        f32x4 accS[16];
#pragma unroll
        for (int st = 0; st < 16; st++) accS[st] = (f32x4){0.f, 0.f, 0.f, 0.f};
#pragma unroll
        for (int st = 0; st < 16; st++) {
            if (st <= st_max) {
                short8 bk0 = *(const short8*)(&Kl[st * 1024 + lane * 8]);
                short8 bk1 = *(const short8*)(&Kl[st * 1024 + 512 + lane * 8]);
                accS[st] = __builtin_amdgcn_mfma_f32_16x16x32_bf16(aq0, bk0, accS[st], 0, 0, 0);
                accS[st] = __builtin_amdgcn_mfma_f32_16x16x32_bf16(aq1, bk1, accS[st], 0, 0, 0);
            }
        }

        float inv[4];
#pragma unroll
        for (int r = 0; r < 4; r++) {
            int row = qrow0 + quad * 4 + r;
            float mx = -INFINITY;
#pragma unroll
            for (int st = 0; st < 16; st++) {
                if (st <= st_max) {
                    int col = st * 16 + c16;
                    float a = (col <= row) ? accS[st][r] * 0.125f : -INFINITY;
                    accS[st][r] = a;
                    mx = fmaxf(mx, a);
                }
            }
#pragma unroll
            for (int off = 8; off; off >>= 1) mx = fmaxf(mx, __shfl_xor(mx, off));
            float sum = 0.f;
#pragma unroll
            for (int st = 0; st < 16; st++) {
                if (st < covered) {
                    float e = 0.0f;
                    if (st <= st_max) {
                        e = __expf(accS[st][r] - mx);
                        sum += e;
                    }
                    int c = st * 16 + c16;
                    Pw[(c >> 5) * 512 + (((c >> 3) & 3) * 16 + quad * 4 + r) * 8 + (c & 7)] =
                        f2bf(e);
                }
            }
#pragma unroll
            for (int off = 8; off; off >>= 1) sum += __shfl_xor(sum, off);
            inv[r] = 1.0f / sum;
        }

        f32x4 accO[4];
#pragma unroll
        for (int nt = 0; nt < 4; nt++) accO[nt] = (f32x4){0.f, 0.f, 0.f, 0.f};
#pragma unroll
        for (int kbi = 0; kbi < 8; kbi++) {
            if (kbi < kb_count) {
                short8 ap = *(const short8*)(Pw + kbi * 512 + lane * 8);
#pragma unroll
                for (int nt = 0; nt < 4; nt++) {
                    short8 bv = *(const short8*)(vs + (kbi * 4 + nt) * 512 + lane * 8);
                    accO[nt] = __builtin_amdgcn_mfma_f32_16x16x32_bf16(ap, bv, accO[nt], 0, 0, 0);
                }
            }
        }

#pragma unroll
        for (int nt = 0; nt < 4; nt++) {
#pragma unroll
            for (int r = 0; r < 4; r++) {
                int t = qrow0 + quad * 4 + r;
                int d = nt * 16 + c16;
                o[(((size_t)b * Tn + t) * Hn + hh) * HSn + d] =
                    __float2bfloat16(accO[nt][r] * inv[r]);
            }
        }
    }
}

extern "C" void kernel_launch(void* const* d_in, const int* in_sizes, int n_in,
                              void* d_out, int out_size, void* d_ws, size_t ws_size,
                              hipStream_t stream) {
    const float* x  = (const float*)d_in[0];
    const float* Wq = (const float*)d_in[1];
    const float* Wk = (const float*)d_in[2];
    const float* Wv = (const float*)d_in[3];
    const float* Wp = (const float*)d_in[4];
    const float* bp = (const float*)d_in[5];
    const float* W1 = (const float*)d_in[6];
    const float* b1 = (const float*)d_in[7];
    const float* W2 = (const float*)d_in[8];
    const float* b2 = (const float*)d_in[9];
    const float* g1 = (const float*)d_in[10];
    const float* be1 = (const float*)d_in[11];
    const float* g2 = (const float*)d_in[12];
    const float* be2 = (const float*)d_in[13];

    const size_t M = (size_t)Bn * Tn;  // 16384
    __hip_bfloat16* ws  = (__hip_bfloat16*)d_ws;
    __hip_bfloat16* h   = ws;               // M*384 bf16 (LN1 out; reused as h2)
    __hip_bfloat16* big = h + M * Cn;       // M*1536 bf16: qkv (3*SECn; v packed) then y1
    __hip_bfloat16* o   = big + M * FFn;    // M*384 bf16 attention output [b,t,h,d]
    __hip_bfloat16* pQKV = o + M * Cn;      // 384*1152
    __hip_bfloat16* pWp  = pQKV + Cn * 1152;
    __hip_bfloat16* pW1  = pWp + Cn * Cn;
    __hip_bfloat16* pW2  = pW1 + Cn * FFn;

    float* x2 = (float*)d_out;

    pack_qkv_kernel<<<(Cn * 1152 + 255) / 256, 256, 0, stream>>>(Wq, Wk, Wv, pQKV);
    pack_b_kernel<<<(Cn * Cn + 255) / 256, 256, 0, stream>>>(Wp, pWp, Cn, Cn);
    pack_b_kernel<<<(Cn * FFn + 255) / 256, 256, 0, stream>>>(W1, pW1, Cn, FFn);
    pack_b_kernel<<<(FFn * Cn + 255) / 256, 256, 0, stream>>>(W2, pW2, FFn, Cn);

    // 1) h = LN1(x)
    ln_bf16_kernel<<<M, 64, 0, stream>>>(x, g1, be1, h);
    // 2) qkv  (GX=18 -> grid 2304); v section written fragment-packed
    gemm_mfma<Cn, 1152, 0><<<2304, 256, 0, stream>>>(h, pQKV, nullptr, nullptr, nullptr, big);
    // 3) attention: one block per (b,h), K staged in LDS
    attn_mfma_kernel<<<Bn * Hn, 256, 0, stream>>>(big, big + SECn, big + 2 * SECn, o);
    // 4) x2 = x + o@Wp + bp   (GX=6 -> 768)
    gemm_mfma<Cn, Cn, 1><<<768, 256, 0, stream>>>(o, pWp, bp, x, x2, nullptr);
    // 5) h2 = LN2(x2)
    ln_bf16_kernel<<<M, 64, 0, stream>>>(x2, g2, be2, h);
    // 6) y1 = relu(h2 @ W1 + b1)  (GX=24 -> 3072)
    gemm_mfma<Cn, FFn, 2><<<3072, 256, 0, stream>>>(h, pW1, b1, nullptr, nullptr, big);
    // 7) out = x2 + y1 @ W2 + b2  (GX=6 -> 768)
    gemm_mfma<FFn, Cn, 1><<<768, 256, 0, stream>>>(big, pW2, b2, x2, x2, nullptr);
}

// Round 10
// 272.184 us; speedup vs baseline: 1.1255x; 1.1255x over previous
//
#include <hip/hip_runtime.h>
#include <hip/hip_bf16.h>
#include <math.h>

#define Bn 64
#define Tn 256
#define Cn 384
#define Hn 6
#define HSn 64
#define FFn 1536
#define EPSn 1e-3f
#define SECn 6291456  // B*H*T*HS = one q/k/v section, elements

typedef __attribute__((ext_vector_type(4))) float f32x4;
typedef __attribute__((ext_vector_type(2))) float f32x2;
typedef __attribute__((ext_vector_type(8))) short short8;
typedef __attribute__((ext_vector_type(4))) short short4v;
typedef __attribute__((ext_vector_type(2))) short short2v;

__device__ __forceinline__ void async_copy16(void* lds, const void* g) {
    __builtin_amdgcn_global_load_lds(
        (const __attribute__((address_space(1))) void*)g,
        (__attribute__((address_space(3))) void*)lds, 16, 0, 0);
}

__device__ __forceinline__ short f2bf(float v) {
    __hip_bfloat16 h = __float2bfloat16(v);
    return *(short*)&h;
}

// Packed-A layout for [M x K] bf16: fragment block (mt, kc) of 1 KB:
//   addr = ((mt * (K/32) + kc) * 512) + lane*8 + j
//   value = A[mt*16 + (lane&15)][kc*32 + (lane>>4)*8 + j]

// ---------------- LayerNorm -> packed-A bf16 (block = 16 rows = one m-tile) ----------------
__global__ __launch_bounds__(256) void ln_pack_kernel(const float* __restrict__ x,
                                                      const float* __restrict__ g,
                                                      const float* __restrict__ be,
                                                      __hip_bfloat16* __restrict__ outPk) {
    int mt = blockIdx.x;
    int tid = threadIdx.x;
    int lane = tid & 63, wave = tid >> 6;
    __shared__ short rows[16 * 392];  // stride 392 shorts (784 B, 16B-aligned per row)
#pragma unroll
    for (int i = 0; i < 4; i++) {
        int r = wave * 4 + i;
        const float* xr = x + ((size_t)mt * 16 + r) * Cn;
        f32x4 a = *(const f32x4*)(xr + lane * 4);
        f32x2 b = *(const f32x2*)(xr + 256 + lane * 2);
        float s = a.x + a.y + a.z + a.w + b.x + b.y;
#pragma unroll
        for (int off = 32; off; off >>= 1) s += __shfl_xor(s, off);
        float mu = s * (1.0f / Cn);
        f32x4 da = a - mu;
        f32x2 db = b - mu;
        float sq = da.x * da.x + da.y * da.y + da.z * da.z + da.w * da.w + db.x * db.x + db.y * db.y;
#pragma unroll
        for (int off = 32; off; off >>= 1) sq += __shfl_xor(sq, off);
        float rs = rsqrtf(sq * (1.0f / Cn) + EPSn);
        f32x4 g4 = *(const f32x4*)(g + lane * 4);
        f32x2 g2 = *(const f32x2*)(g + 256 + lane * 2);
        f32x4 e4 = *(const f32x4*)(be + lane * 4);
        f32x2 e2 = *(const f32x2*)(be + 256 + lane * 2);
        f32x4 y4 = da * rs * g4 + e4;
        f32x2 y2 = db * rs * g2 + e2;
        short4v o4 = {f2bf(y4.x), f2bf(y4.y), f2bf(y4.z), f2bf(y4.w)};
        *(short4v*)(&rows[r * 392 + lane * 4]) = o4;
        short2v o2 = {f2bf(y2.x), f2bf(y2.y)};
        *(short2v*)(&rows[r * 392 + 256 + lane * 2]) = o2;
    }
    __syncthreads();
    int r = lane & 15, q = lane >> 4;
#pragma unroll
    for (int p = 0; p < 3; p++) {
        int f = p * 4 + (tid >> 6);  // fragment (k-chunk) 0..11
        short8 v = *(const short8*)(&rows[r * 392 + f * 32 + q * 8]);
        *(short8*)((short*)outPk + ((size_t)mt * 12 + f) * 512 + lane * 8) = v;
    }
}

// ---------------- Pack a [K,N] row-major fp32 weight into MFMA B-fragment order ----------------
__global__ __launch_bounds__(256) void pack_b_kernel(const float* __restrict__ W,
                                                     __hip_bfloat16* __restrict__ out,
                                                     int K, int N) {
    int id = blockIdx.x * 256 + threadIdx.x;
    if (id >= K * N) return;
    int tile = id >> 9, lane = (id >> 3) & 63, j = id & 7;
    int ntiles = N >> 4;
    int k = (tile / ntiles) * 32 + ((lane >> 4) << 3) + j;
    int n = (tile % ntiles) * 16 + (lane & 15);
    out[id] = __float2bfloat16(W[(size_t)k * N + n]);
}

// ---------------- Pack fused [Wq|Wk|Wv] into one B [K=384, N=1152] ----------------
__global__ __launch_bounds__(256) void pack_qkv_kernel(const float* __restrict__ Wq,
                                                       const float* __restrict__ Wk,
                                                       const float* __restrict__ Wv,
                                                       __hip_bfloat16* __restrict__ out) {
    int id = blockIdx.x * 256 + threadIdx.x;
    if (id >= Cn * 1152) return;
    int tile = id >> 9, lane = (id >> 3) & 63, j = id & 7;
    int k = (tile / 72) * 32 + ((lane >> 4) << 3) + j;
    int n = (tile % 72) * 16 + (lane & 15);
    int sec = n / Cn, rem = n % Cn;
    int hh = rem >> 6, d = rem & 63;
    const float* W = (sec == 0) ? Wq : ((sec == 1) ? Wk : Wv);
    out[id] = __float2bfloat16(W[((size_t)hh * Cn + k) * HSn + d]);
}

// ---------------- Barrier-free streaming MFMA GEMM: C = Apk @ Bpk ----------------
// Block tile 128(M) x 64(N). A pre-packed in A-frag blocks, B pre-packed in B-frag
// tiles — both read fragment-direct from global (contiguous 1 KB/wave loads, zero
// LDS staging, zero __syncthreads in the K-loop -> compiler pipelines vmcnt freely).
// LDS used only for per-wave epilogue transpose strips (no barriers).
template <int KK, int NN, int EPI>
__global__ __launch_bounds__(256) void gemm_mfma(const __hip_bfloat16* __restrict__ Apk,
                                                 const __hip_bfloat16* __restrict__ Bp,
                                                 const float* __restrict__ bias,
                                                 const float* __restrict__ resid,
                                                 float* __restrict__ outF,
                                                 __hip_bfloat16* __restrict__ outB) {
    constexpr int GX = NN / 64;
    constexpr int K32 = KK / 32;
    constexpr int NT16 = NN / 16;
    __shared__ __align__(16) char lds_raw[4 * 4864];  // per-wave transpose strips

    int l = blockIdx.x;
    int xcd = l & 7, i = l >> 3;
    int rowblk = xcd * 16 + i / GX;
    int colblk = i - (i / GX) * GX;

    int lane = threadIdx.x & 63, wave = threadIdx.x >> 6;
    int lrow = lane & 15, lquad = lane >> 4;
    int m0 = rowblk * 128;
    int n0 = colblk * 64;
    int mt0 = (m0 >> 4) + wave * 2;  // wave's two m-tiles: mt0, mt0+1

    f32x4 acc[2][4];
#pragma unroll
    for (int st = 0; st < 2; st++)
#pragma unroll
        for (int nt = 0; nt < 4; nt++) acc[st][nt] = (f32x4){0.f, 0.f, 0.f, 0.f};

    const short* a0p = (const short*)Apk + ((size_t)mt0 * K32) * 512 + lane * 8;
    const short* a1p = a0p + (size_t)K32 * 512;
    const short* bp0 = (const short*)Bp + ((size_t)(n0 >> 4)) * 512 + lane * 8;

#pragma unroll 6
    for (int kc = 0; kc < K32; kc++) {
        short8 af0 = *(const short8*)(a0p + (size_t)kc * 512);
        short8 af1 = *(const short8*)(a1p + (size_t)kc * 512);
#pragma unroll
        for (int nt = 0; nt < 4; nt++) {
            short8 bf = *(const short8*)(bp0 + ((size_t)kc * NT16 + nt) * 512);
            acc[0][nt] = __builtin_amdgcn_mfma_f32_16x16x32_bf16(af0, bf, acc[0][nt], 0, 0, 0);
            acc[1][nt] = __builtin_amdgcn_mfma_f32_16x16x32_bf16(af1, bf, acc[1][nt], 0, 0, 0);
        }
    }

    if (EPI == 1) {
        // fp32 out = resid + acc + bias (row-major), strip-by-strip (16 x 64 fp32, stride 76)
        float* twf = (float*)(lds_raw + wave * 4864);
        float bnv[4];
#pragma unroll
        for (int nt = 0; nt < 4; nt++) bnv[nt] = bias[n0 + nt * 16 + lrow];
#pragma unroll
        for (int st = 0; st < 2; st++) {
            int mbase = m0 + (2 * wave + st) * 16;
#pragma unroll
            for (int nt = 0; nt < 4; nt++)
#pragma unroll
                for (int r = 0; r < 4; r++)
                    twf[(lquad * 4 + r) * 76 + nt * 16 + lrow] = acc[st][nt][r] + bnv[nt];
            int row = lane >> 2, seg = lane & 3;
            int m = mbase + row;
            const float* rrow = resid + (size_t)m * NN + n0 + seg * 16;
            float* orow = outF + (size_t)m * NN + n0 + seg * 16;
#pragma unroll
            for (int c = 0; c < 4; c++) {
                f32x4 vv = *(const f32x4*)(&twf[row * 76 + seg * 16 + c * 4]);
                f32x4 rv = *(const f32x4*)(rrow + c * 4);
                *(f32x4*)(orow + c * 4) = vv + rv;
            }
            __builtin_amdgcn_s_waitcnt(0);  // wave-local strip reuse
        }
    } else {
        // bf16 cases: full 32 rows x 64 cols per-wave strip (stride 72 shorts, 16B-aligned rows)
        short* tws = (short*)(lds_raw + wave * 4864);
        float bnv[4];
        if (EPI == 2) {
#pragma unroll
            for (int nt = 0; nt < 4; nt++) bnv[nt] = bias[n0 + nt * 16 + lrow];
        }
#pragma unroll
        for (int st = 0; st < 2; st++)
#pragma unroll
            for (int nt = 0; nt < 4; nt++)
#pragma unroll
                for (int r = 0; r < 4; r++) {
                    float v = acc[st][nt][r];
                    if (EPI == 2) v = fmaxf(v + bnv[nt], 0.0f);
                    tws[(st * 16 + lquad * 4 + r) * 72 + nt * 16 + lrow] = f2bf(v);
                }
        if (EPI == 2) {
            // y1 -> packed-A layout for FF2 (K_ff2 = NN, so K32_out = NN/32)
#pragma unroll
            for (int st2 = 0; st2 < 2; st2++) {
                int mt = (m0 >> 4) + wave * 2 + st2;
#pragma unroll
                for (int kcl = 0; kcl < 2; kcl++) {
                    int kc = (n0 >> 5) + kcl;
                    short8 v = *(const short8*)(
                        &tws[(st2 * 16 + (lane & 15)) * 72 + kcl * 32 + (lane >> 4) * 8]);
                    *(short8*)((short*)outB + ((size_t)mt * (NN / 32) + kc) * 512 + lane * 8) = v;
                }
            }
        } else {
            // EPI 0: q,k scatter row-major [B,H,T,HS]; V pre-packed B-frag tiles
            int sec = n0 / 384;
            int rem0 = n0 - sec * 384;
            int hh = rem0 >> 6;  // wave-uniform
            if (sec < 2) {
                int row = lane >> 1, seg = lane & 1;
                int m = m0 + wave * 32 + row;
                int b = m >> 8, t = m & 255;
                short* orow = (short*)outB + (size_t)sec * SECn +
                              ((((size_t)b * Hn + hh) << 8) + t) * HSn + seg * 32;
#pragma unroll
                for (int c = 0; c < 4; c++) {
                    short8 v8 = *(const short8*)(&tws[row * 72 + seg * 32 + c * 8]);
                    *(short8*)(orow + c * 8) = v8;
                }
            } else {
                int b = m0 >> 8;
                int t_base = (m0 & 255) + wave * 32;
                int bh2 = b * Hn + hh;
                short* vout = (short*)outB + (size_t)2 * SECn + (size_t)bh2 * 16384 +
                              (size_t)((t_base >> 5) * 4) * 512;
#pragma unroll
                for (int dt = 0; dt < 4; dt++) {
                    short8 v8;
#pragma unroll
                    for (int j = 0; j < 8; j++) {
                        int t_loc = ((lane >> 4) << 3) + j;
                        v8[j] = tws[t_loc * 72 + dt * 16 + (lane & 15)];
                    }
                    *(short8*)(vout + dt * 512 + lane * 8) = v8;
                }
            }
        }
    }
}

// ---------------- Flash-style MFMA attention: one block per (b,h), K in LDS ----------------
// O written in packed-A layout (proj GEMM consumes it fragment-direct).
__global__ __launch_bounds__(256) void attn_mfma_kernel(const __hip_bfloat16* __restrict__ q,
                                                        const __hip_bfloat16* __restrict__ k,
                                                        const __hip_bfloat16* __restrict__ vp,
                                                        __hip_bfloat16* __restrict__ o) {
    __shared__ short Kl[16 * 1024];  // 32 KB: K tiles [st][chunk<2][512]
    __shared__ short Pl[4 * 4096];   // 32 KB: per-wave P in A-frag layout (reused for O strip)
    int bh = blockIdx.x;
    int b = bh / Hn, hh = bh - b * Hn;
    int tid = threadIdx.x;
    int lane = tid & 63, wave = tid >> 6;
    int c16 = lane & 15, quad = lane >> 4;

    const short* qs = (const short*)q + (size_t)bh * Tn * HSn;
    const short* ks = (const short*)k + (size_t)bh * Tn * HSn;
    const short* vs = (const short*)vp + (size_t)bh * 16384;  // packed B-frag tiles

#pragma unroll
    for (int i = 0; i < 4; i++) {
        int st = wave * 4 + i;
        const short* g0 = ks + (st * 16 + c16) * HSn + quad * 8;
        async_copy16(&Kl[st * 1024], g0);
        async_copy16(&Kl[st * 1024 + 512], g0 + 32);
    }
    __syncthreads();

    short* Pw = Pl + wave * 4096;

#pragma unroll
    for (int j = 0; j < 4; j++) {
        int qt = j * 4 + wave;
        int qrow0 = qt * 16;
        int st_max = qt;
        int kb_count = (st_max + 2) >> 1;
        int covered = kb_count * 2;

        const short* qrow = qs + (qrow0 + c16) * HSn + quad * 8;
        short8 aq0 = *(const short8*)(qrow);
        short8 aq1 = *(const short8*)(qrow + 32);

        f32x4 accS[16];
#pragma unroll
        for (int st = 0; st < 16; st++) accS[st] = (f32x4){0.f, 0.f, 0.f, 0.f};
#pragma unroll
        for (int st = 0; st < 16; st++) {
            if (st <= st_max) {
                short8 bk0 = *(const short8*)(&Kl[st * 1024 + lane * 8]);
                short8 bk1 = *(const short8*)(&Kl[st * 1024 + 512 + lane * 8]);
                accS[st] = __builtin_amdgcn_mfma_f32_16x16x32_bf16(aq0, bk0, accS[st], 0, 0, 0);
                accS[st] = __builtin_amdgcn_mfma_f32_16x16x32_bf16(aq1, bk1, accS[st], 0, 0, 0);
            }
        }

        float inv[4];
#pragma unroll
        for (int r = 0; r < 4; r++) {
            int row = qrow0 + quad * 4 + r;
            float mx = -INFINITY;
#pragma unroll
            for (int st = 0; st < 16; st++) {
                if (st <= st_max) {
                    int col = st * 16 + c16;
                    float a = (col <= row) ? accS[st][r] * 0.125f : -INFINITY;
                    accS[st][r] = a;
                    mx = fmaxf(mx, a);
                }
            }
#pragma unroll
            for (int off = 8; off; off >>= 1) mx = fmaxf(mx, __shfl_xor(mx, off));
            float sum = 0.f;
#pragma unroll
            for (int st = 0; st < 16; st++) {
                if (st < covered) {
                    float e = 0.0f;
                    if (st <= st_max) {
                        e = __expf(accS[st][r] - mx);
                        sum += e;
                    }
                    int c = st * 16 + c16;
                    Pw[(c >> 5) * 512 + (((c >> 3) & 3) * 16 + quad * 4 + r) * 8 + (c & 7)] =
                        f2bf(e);
                }
            }
#pragma unroll
            for (int off = 8; off; off >>= 1) sum += __shfl_xor(sum, off);
            inv[r] = 1.0f / sum;
        }

        f32x4 accO[4];
#pragma unroll
        for (int nt = 0; nt < 4; nt++) accO[nt] = (f32x4){0.f, 0.f, 0.f, 0.f};
#pragma unroll
        for (int kbi = 0; kbi < 8; kbi++) {
            if (kbi < kb_count) {
                short8 ap = *(const short8*)(Pw + kbi * 512 + lane * 8);
#pragma unroll
                for (int nt = 0; nt < 4; nt++) {
                    short8 bv = *(const short8*)(vs + (kbi * 4 + nt) * 512 + lane * 8);
                    accO[nt] = __builtin_amdgcn_mfma_f32_16x16x32_bf16(ap, bv, accO[nt], 0, 0, 0);
                }
            }
        }

        // ---- O epilogue: C-layout -> strip (stride 72) -> packed-A global ----
#pragma unroll
        for (int nt = 0; nt < 4; nt++)
#pragma unroll
            for (int r = 0; r < 4; r++)
                Pw[(quad * 4 + r) * 72 + nt * 16 + c16] = f2bf(accO[nt][r] * inv[r]);
        int mt = (b << 4) + qt;  // (b*256 + qt*16) / 16
#pragma unroll
        for (int kcl = 0; kcl < 2; kcl++) {
            short8 v = *(const short8*)(&Pw[(lane & 15) * 72 + kcl * 32 + (lane >> 4) * 8]);
            *(short8*)((short*)o + ((size_t)mt * 12 + hh * 2 + kcl) * 512 + lane * 8) = v;
        }
    }
}

extern "C" void kernel_launch(void* const* d_in, const int* in_sizes, int n_in,
                              void* d_out, int out_size, void* d_ws, size_t ws_size,
                              hipStream_t stream) {
    const float* x  = (const float*)d_in[0];
    const float* Wq = (const float*)d_in[1];
    const float* Wk = (const float*)d_in[2];
    const float* Wv = (const float*)d_in[3];
    const float* Wp = (const float*)d_in[4];
    const float* bp = (const float*)d_in[5];
    const float* W1 = (const float*)d_in[6];
    const float* b1 = (const float*)d_in[7];
    const float* W2 = (const float*)d_in[8];
    const float* b2 = (const float*)d_in[9];
    const float* g1 = (const float*)d_in[10];
    const float* be1 = (const float*)d_in[11];
    const float* g2 = (const float*)d_in[12];
    const float* be2 = (const float*)d_in[13];

    const size_t M = (size_t)Bn * Tn;  // 16384
    __hip_bfloat16* ws  = (__hip_bfloat16*)d_ws;
    __hip_bfloat16* h   = ws;               // M*384 bf16 packed-A (LN1 out; reused as h2)
    __hip_bfloat16* big = h + M * Cn;       // M*1536 bf16: q,k row-major + v packed; then y1 packed
    __hip_bfloat16* o   = big + M * FFn;    // M*384 bf16 attention output, packed-A
    __hip_bfloat16* pQKV = o + M * Cn;      // 384*1152 B-packed
    __hip_bfloat16* pWp  = pQKV + Cn * 1152;
    __hip_bfloat16* pW1  = pWp + Cn * Cn;
    __hip_bfloat16* pW2  = pW1 + Cn * FFn;

    float* x2 = (float*)d_out;

    pack_qkv_kernel<<<(Cn * 1152 + 255) / 256, 256, 0, stream>>>(Wq, Wk, Wv, pQKV);
    pack_b_kernel<<<(Cn * Cn + 255) / 256, 256, 0, stream>>>(Wp, pWp, Cn, Cn);
    pack_b_kernel<<<(Cn * FFn + 255) / 256, 256, 0, stream>>>(W1, pW1, Cn, FFn);
    pack_b_kernel<<<(FFn * Cn + 255) / 256, 256, 0, stream>>>(W2, pW2, FFn, Cn);

    // 1) h = LN1(x), packed-A
    ln_pack_kernel<<<M / 16, 256, 0, stream>>>(x, g1, be1, h);
    // 2) qkv  (GX=18 -> 2304 blocks); q,k row-major scatter, v fragment-packed
    gemm_mfma<Cn, 1152, 0><<<2304, 256, 0, stream>>>(h, pQKV, nullptr, nullptr, nullptr, big);
    // 3) attention: one block per (b,h); O written packed-A
    attn_mfma_kernel<<<Bn * Hn, 256, 0, stream>>>(big, big + SECn, big + 2 * SECn, o);
    // 4) x2 = x + o@Wp + bp   (GX=6 -> 768 blocks), fp32 row-major
    gemm_mfma<Cn, Cn, 1><<<768, 256, 0, stream>>>(o, pWp, bp, x, x2, nullptr);
    // 5) h2 = LN2(x2), packed-A
    ln_pack_kernel<<<M / 16, 256, 0, stream>>>(x2, g2, be2, h);
    // 6) y1 = relu(h2 @ W1 + b1)  (GX=24 -> 3072 blocks), packed-A output
    gemm_mfma<Cn, FFn, 2><<<3072, 256, 0, stream>>>(h, pW1, b1, nullptr, nullptr, big);
    // 7) out = x2 + y1 @ W2 + b2  (GX=6 -> 768 blocks), fp32 row-major
    gemm_mfma<FFn, Cn, 1><<<768, 256, 0, stream>>>(big, pW2, b2, x2, x2, nullptr);
}